// Round 12
// baseline (40.611 us; speedup 1.0000x reference)
//
#include <hip/hip_runtime.h>
#include <math.h>

#define BATCH 32
#define NSAMP 262144
#define NKNOT 256
#define EPSV  0.001f
#define CH    16                  // samples per chunk = 64 B = one cache line
#define NCROW (NSAMP / CH)        // 16384 chunks per row
#define CPBLK 512                 // chunks per block
#define BPRB  (NCROW / CPBLK)     // 32 blocks per row
#define NBLK  (BATCH * NCROW / CPBLK)   // 1024 blocks
#define TC    (BATCH * NCROW)     // 524288 chunks total

__device__ __forceinline__ float fast_tanh(float x) {
    // tanh(x) = 1 - 2/(exp(2x)+1); branch-free, ~1e-7 abs error
    float e = __expf(2.0f * x);
    float r = __builtin_amdgcn_rcpf(e + 1.0f);
    return fmaf(-2.0f, r, 1.0f);
}

// ---------------------------------------------------------------------------
// Kernel 1: 256 thr × 2 chunks (ILP 2). Per-chunk exclusive prefix C + G.
// ---------------------------------------------------------------------------
__global__ __launch_bounds__(256, 4) void k_agg(
    const float* __restrict__ x,
    const float* __restrict__ cl,     // [BATCH][NKNOT][5]
    float* __restrict__ Cb,           // [6][TC]
    float* __restrict__ G)            // [6][NBLK]
{
    __shared__ float wag[4][6];
    const int tid = threadIdx.x;
    const int b = blockIdx.x;
    const int lane = tid & 63, wid = tid >> 6;

    const int chunk0 = b * CPBLK + 2 * tid;   // and chunk0+1
    const float4* xp = (const float4*)(x + (size_t)chunk0 * CH);

    // knot coefficients (channels 0,1) for both chunks
    const float scale = 255.0f / 262143.0f;
    int r = chunk0 >> 14;
    const float* kb = cl + (size_t)r * NKNOT * 5;

    int cA = chunk0 & (NCROW - 1);
    float posA = (float)(cA * CH) * scale;
    float fiA = floorf(posA);
    int iA0 = (int)fiA;
    float wA = posA - fiA;
    int iA1 = min(iA0 + 1, NKNOT - 1), iA2 = min(iA0 + 2, NKNOT - 1);
    float a_k00 = kb[iA0*5+0], a_k01 = kb[iA1*5+0], a_k02 = kb[iA2*5+0];
    float a_k10 = kb[iA0*5+1], a_k11 = kb[iA1*5+1], a_k12 = kb[iA2*5+1];
    float a_d0A = a_k01-a_k00, a_d0B = a_k02-a_k01;
    float a_d1A = a_k11-a_k10, a_d1B = a_k12-a_k11;

    int cB = cA + 1;
    float posB = (float)(cB * CH) * scale;
    float fiB = floorf(posB);
    int iB0 = (int)fiB;
    float wB = posB - fiB;
    int iB1 = min(iB0 + 1, NKNOT - 1), iB2 = min(iB0 + 2, NKNOT - 1);
    float b_k00 = kb[iB0*5+0], b_k01 = kb[iB1*5+0], b_k02 = kb[iB2*5+0];
    float b_k10 = kb[iB0*5+1], b_k11 = kb[iB1*5+1], b_k12 = kb[iB2*5+1];
    float b_d0A = b_k01-b_k00, b_d0B = b_k02-b_k01;
    float b_d1A = b_k11-b_k10, b_d1B = b_k12-b_k11;

    // build both chunk maps with interleaved (independent) chains
    const float stab = 1.0f - EPSV, stab2 = 2.0f * stab;
    float ap1 = 0.f, ap2 = 0.f, aA1 = 1.f, aA2 = 0.f, aB1 = 0.f, aB2 = 1.f;
    float bp1 = 0.f, bp2 = 0.f, bA1 = 1.f, bA2 = 0.f, bB1 = 0.f, bB2 = 1.f;
    #pragma unroll
    for (int v4 = 0; v4 < 4; ++v4) {
        float4 xqa = xp[v4];
        float4 xqb = xp[4 + v4];
        #pragma unroll
        for (int q = 0; q < 4; ++q) {
            int j = v4 * 4 + q;
            // chunk A sample
            {
                float w = fmaf((float)j, scale, wA);
                bool sel = w >= 1.0f;
                float wu = sel ? w - 1.0f : w;
                float l0 = fmaf(wu, sel ? a_d0B : a_d0A, sel ? a_k01 : a_k00);
                float l1 = fmaf(wu, sel ? a_d1B : a_d1A, sel ? a_k11 : a_k10);
                float a1 = stab2 * fast_tanh(l0);
                float a1a = fabsf(a1);
                float a2 = 0.5f * fmaf((2.0f - a1a) * stab, fast_tanh(l1), a1a);
                float p  = fmaf(-a2, ap2, (&xqa.x)[q]);  p = fmaf(-a1, ap1, p);
                float hA = fmaf(-a1, aA1, -a2 * aA2);
                float hB = fmaf(-a1, aB1, -a2 * aB2);
                ap2 = ap1; ap1 = p;
                aA2 = aA1; aA1 = hA;
                aB2 = aB1; aB1 = hB;
            }
            // chunk B sample (independent chain)
            {
                float w = fmaf((float)j, scale, wB);
                bool sel = w >= 1.0f;
                float wu = sel ? w - 1.0f : w;
                float l0 = fmaf(wu, sel ? b_d0B : b_d0A, sel ? b_k01 : b_k00);
                float l1 = fmaf(wu, sel ? b_d1B : b_d1A, sel ? b_k11 : b_k10);
                float a1 = stab2 * fast_tanh(l0);
                float a1a = fabsf(a1);
                float a2 = 0.5f * fmaf((2.0f - a1a) * stab, fast_tanh(l1), a1a);
                float p  = fmaf(-a2, bp2, (&xqb.x)[q]);  p = fmaf(-a1, bp1, p);
                float hA = fmaf(-a1, bA1, -a2 * bA2);
                float hB = fmaf(-a1, bB1, -a2 * bB2);
                bp2 = bp1; bp1 = p;
                bA2 = bA1; bA1 = hA;
                bB2 = bB1; bB1 = hB;
            }
        }
    }
    // chunk A map (kept for C of chunk B)
    float Ma00 = aA1, Ma01 = aB1, Ma10 = aA2, Ma11 = aB2, Mav0 = ap1, Mav1 = ap2;
    // pair map = Mb ∘ Ma
    float L00 = bA1*Ma00 + bB1*Ma10;
    float L01 = bA1*Ma01 + bB1*Ma11;
    float L10 = bA2*Ma00 + bB2*Ma10;
    float L11 = bA2*Ma01 + bB2*Ma11;
    float Lv0 = fmaf(bA1, Mav0, fmaf(bB1, Mav1, bp1));
    float Lv1 = fmaf(bA2, Mav0, fmaf(bB2, Mav1, bp2));

    // wave-inclusive scan over pair maps
    #pragma unroll
    for (int d = 1; d < 64; d <<= 1) {
        float o00 = __shfl_up(L00, d), o01 = __shfl_up(L01, d);
        float o10 = __shfl_up(L10, d), o11 = __shfl_up(L11, d);
        float ov0 = __shfl_up(Lv0, d), ov1 = __shfl_up(Lv1, d);
        if (lane >= d) {
            float n00 = L00 * o00 + L01 * o10;
            float n01 = L00 * o01 + L01 * o11;
            float n10 = L10 * o00 + L11 * o10;
            float n11 = L10 * o01 + L11 * o11;
            float nv0 = fmaf(L00, ov0, fmaf(L01, ov1, Lv0));
            float nv1 = fmaf(L10, ov0, fmaf(L11, ov1, Lv1));
            L00 = n00; L01 = n01; L10 = n10; L11 = n11; Lv0 = nv0; Lv1 = nv1;
        }
    }
    if (lane == 63) {
        wag[wid][0] = L00; wag[wid][1] = L01; wag[wid][2] = L10;
        wag[wid][3] = L11; wag[wid][4] = Lv0; wag[wid][5] = Lv1;
    }
    __syncthreads();

    // P = compose of earlier waves' aggregates
    float P00 = 1.f, P01 = 0.f, P10 = 0.f, P11 = 1.f, Pv0 = 0.f, Pv1 = 0.f;
    for (int w2 = 0; w2 < wid; ++w2) {
        float a00 = wag[w2][0], a01 = wag[w2][1], a10 = wag[w2][2];
        float a11 = wag[w2][3], av0 = wag[w2][4], av1 = wag[w2][5];
        float n00 = a00 * P00 + a01 * P10;
        float n01 = a00 * P01 + a01 * P11;
        float n10 = a10 * P00 + a11 * P10;
        float n11 = a10 * P01 + a11 * P11;
        float nv0 = fmaf(a00, Pv0, fmaf(a01, Pv1, av0));
        float nv1 = fmaf(a10, Pv0, fmaf(a11, Pv1, av1));
        P00 = n00; P01 = n01; P10 = n10; P11 = n11; Pv0 = nv0; Pv1 = nv1;
    }
    // pair-exclusive E; C0 = E ∘ P; C1 = Ma ∘ C0
    float E00 = __shfl_up(L00, 1), E01 = __shfl_up(L01, 1);
    float E10 = __shfl_up(L10, 1), E11 = __shfl_up(L11, 1);
    float Ev0 = __shfl_up(Lv0, 1), Ev1 = __shfl_up(Lv1, 1);
    if (lane == 0) { E00 = 1.f; E01 = 0.f; E10 = 0.f; E11 = 1.f; Ev0 = 0.f; Ev1 = 0.f; }
    float C00 = E00 * P00 + E01 * P10;
    float C01 = E00 * P01 + E01 * P11;
    float C10 = E10 * P00 + E11 * P10;
    float C11 = E10 * P01 + E11 * P11;
    float Cv0 = fmaf(E00, Pv0, fmaf(E01, Pv1, Ev0));
    float Cv1 = fmaf(E10, Pv0, fmaf(E11, Pv1, Ev1));
    float D00 = Ma00 * C00 + Ma01 * C10;
    float D01 = Ma00 * C01 + Ma01 * C11;
    float D10 = Ma10 * C00 + Ma11 * C10;
    float D11 = Ma10 * C01 + Ma11 * C11;
    float Dv0 = fmaf(Ma00, Cv0, fmaf(Ma01, Cv1, Mav0));
    float Dv1 = fmaf(Ma10, Cv0, fmaf(Ma11, Cv1, Mav1));

    // coalesced float2 stores of C for (chunk0, chunk0+1)
    *(float2*)&Cb[0*TC + chunk0] = make_float2(C00, D00);
    *(float2*)&Cb[1*TC + chunk0] = make_float2(C01, D01);
    *(float2*)&Cb[2*TC + chunk0] = make_float2(C10, D10);
    *(float2*)&Cb[3*TC + chunk0] = make_float2(C11, D11);
    *(float2*)&Cb[4*TC + chunk0] = make_float2(Cv0, Dv0);
    *(float2*)&Cb[5*TC + chunk0] = make_float2(Cv1, Dv1);

    // block aggregate G = L(last) ∘ P
    if (tid == 255) {
        G[0*NBLK + b] = L00 * P00 + L01 * P10;
        G[1*NBLK + b] = L00 * P01 + L01 * P11;
        G[2*NBLK + b] = L10 * P00 + L11 * P10;
        G[3*NBLK + b] = L10 * P01 + L11 * P11;
        G[4*NBLK + b] = fmaf(L00, Pv0, fmaf(L01, Pv1, Lv0));
        G[5*NBLK + b] = fmaf(L10, Pv0, fmaf(L11, Pv1, Lv1));
    }
}

// ---------------------------------------------------------------------------
// Kernel 2: 512 thr × 1 chunk; per-wave redundant row-scan of G; NO barriers
// ---------------------------------------------------------------------------
__global__ __launch_bounds__(512, 4) void k_apply(
    const float* __restrict__ x,
    const float* __restrict__ cl,
    const float* __restrict__ Cb,     // [6][TC]
    const float* __restrict__ G,      // [6][NBLK]
    float* __restrict__ out)
{
    const int tid = threadIdx.x;
    const int b = blockIdx.x;
    const int lane = tid & 63;

    // every wave: scan this row's 32 block aggregates (lanes 0..31 active)
    const int myIdx = b & (BPRB - 1);
    const int rowFirst = b - myIdx;
    float A00 = 1.f, A01 = 0.f, A10 = 0.f, A11 = 1.f, Av0 = 0.f, Av1 = 0.f;
    if (lane < BPRB) {
        int k = rowFirst + lane;
        A00 = G[0*NBLK + k]; A01 = G[1*NBLK + k]; A10 = G[2*NBLK + k];
        A11 = G[3*NBLK + k]; Av0 = G[4*NBLK + k]; Av1 = G[5*NBLK + k];
    }
    #pragma unroll
    for (int d = 1; d < BPRB; d <<= 1) {
        float o00 = __shfl_up(A00, d), o01 = __shfl_up(A01, d);
        float o10 = __shfl_up(A10, d), o11 = __shfl_up(A11, d);
        float ov0 = __shfl_up(Av0, d), ov1 = __shfl_up(Av1, d);
        if (lane >= d) {
            float n00 = A00 * o00 + A01 * o10;
            float n01 = A00 * o01 + A01 * o11;
            float n10 = A10 * o00 + A11 * o10;
            float n11 = A10 * o01 + A11 * o11;
            float nv0 = fmaf(A00, ov0, fmaf(A01, ov1, Av0));
            float nv1 = fmaf(A10, ov0, fmaf(A11, ov1, Av1));
            A00 = n00; A01 = n01; A10 = n10; A11 = n11; Av0 = nv0; Av1 = nv1;
        }
    }
    int src = (myIdx > 0) ? myIdx - 1 : 0;
    float s0 = __shfl(Av0, src);
    float s1 = __shfl(Av1, src);
    if (myIdx == 0) { s0 = 0.f; s1 = 0.f; }

    // knot coefficients (all 5 channels)
    int chunk = b * CPBLK + tid;
    int r = chunk >> 14;
    int c = chunk & (NCROW - 1);
    const float scale = 255.0f / 262143.0f;
    float pos0 = (float)(c * CH) * scale;
    float fiA = floorf(pos0);
    int idxA = (int)fiA;
    float w0v = pos0 - fiA;
    const float* kb = cl + (size_t)r * NKNOT * 5;
    int i1 = min(idxA + 1, NKNOT - 1);
    int i2 = min(idxA + 2, NKNOT - 1);
    float k00 = kb[idxA*5+0], k01 = kb[i1*5+0], k02 = kb[i2*5+0];
    float k10 = kb[idxA*5+1], k11 = kb[i1*5+1], k12 = kb[i2*5+1];
    float k20 = kb[idxA*5+2], k21 = kb[i1*5+2], k22 = kb[i2*5+2];
    float k30 = kb[idxA*5+3], k31 = kb[i1*5+3], k32 = kb[i2*5+3];
    float k40 = kb[idxA*5+4], k41 = kb[i1*5+4], k42 = kb[i2*5+4];
    float d0A = k01-k00, d0B = k02-k01;
    float d1A = k11-k10, d1B = k12-k11;
    float d2A = k21-k20, d2B = k22-k21;
    float d3A = k31-k30, d3B = k32-k31;
    float d4A = k41-k40, d4B = k42-k41;

    // per-chunk C (coalesced loads) -> chunk-start state
    float C00 = Cb[0*TC + chunk], C01 = Cb[1*TC + chunk];
    float C10 = Cb[2*TC + chunk], C11 = Cb[3*TC + chunk];
    float Cv0 = Cb[4*TC + chunk], Cv1 = Cb[5*TC + chunk];
    float y1 = fmaf(C00, s0, fmaf(C01, s1, Cv0));
    float y2 = fmaf(C10, s0, fmaf(C11, s1, Cv1));

    // single apply+FIR pass
    const float stab = 1.0f - EPSV, stab2 = 2.0f * stab;
    const float4* xp = (const float4*)(x + (size_t)chunk * CH);
    float4* op = (float4*)(out + (size_t)chunk * CH);
    #pragma unroll
    for (int v4 = 0; v4 < 4; ++v4) {
        float4 xq = xp[v4];
        float4 ov;
        #pragma unroll
        for (int q = 0; q < 4; ++q) {
            int j = v4 * 4 + q;
            float w = fmaf((float)j, scale, w0v);
            bool sel = w >= 1.0f;
            float wu = sel ? w - 1.0f : w;
            float l0 = fmaf(wu, sel ? d0B : d0A, sel ? k01 : k00);
            float l1 = fmaf(wu, sel ? d1B : d1A, sel ? k11 : k10);
            float b0 = fmaf(wu, sel ? d2B : d2A, sel ? k21 : k20);
            float b1c= fmaf(wu, sel ? d3B : d3A, sel ? k31 : k30);
            float b2c= fmaf(wu, sel ? d4B : d4A, sel ? k41 : k40);
            float a1 = stab2 * fast_tanh(l0);
            float a1a = fabsf(a1);
            float a2 = 0.5f * fmaf((2.0f - a1a) * stab, fast_tanh(l1), a1a);
            float y = fmaf(-a2, y2, (&xq.x)[q]);  y = fmaf(-a1, y1, y);
            (&ov.x)[q] = fmaf(b0, y, fmaf(b1c, y1, b2c * y2));
            y2 = y1; y1 = y;
        }
        op[v4] = ov;
    }
}

extern "C" void kernel_launch(void* const* d_in, const int* in_sizes, int n_in,
                              void* d_out, int out_size, void* d_ws, size_t ws_size,
                              hipStream_t stream) {
    const float* x  = (const float*)d_in[0];   // [32][262144]
    const float* cl = (const float*)d_in[1];   // [32][256][5]
    float* out = (float*)d_out;
    float* Cb = (float*)d_ws;                  // [6][TC] = 12.6 MB
    float* G  = Cb + (size_t)6 * TC;           // [6][NBLK] = 24 KB

    hipLaunchKernelGGL(k_agg,   dim3(NBLK), dim3(256), 0, stream, x, cl, Cb, G);
    hipLaunchKernelGGL(k_apply, dim3(NBLK), dim3(512), 0, stream, x, cl, Cb, G, out);
}